// Round 3
// baseline (67.263 us; speedup 1.0000x reference)
//
#include <hip/hip_runtime.h>
#include <math.h>

// Problem: B=64, T=512, D=1024.
//   v[b,d]     = sum_e W[d,e] * x[b,T-1,e]
//   scores[b,t]= sum_d x[b,t,d] * v[b,d]          (t in 0..510)
//   alpha      = softmax_t(scores)
//   c[b,d]     = sum_t alpha[b,t] * x[b,t,d]
//   out[b]     = concat(c[b,:], x[b,T-1,:])       (64 x 2048 fp32)

#define BB 64
#define TT 512
#define DD 1024
#define TH 511           // history rows
#define CHUNK 32         // t-rows per block
#define SUB 16           // online-softmax sub-chunk
#define NCHUNK 16        // 511 = 15*32 + 31 -> chunk 15 has 31 rows

// workspace layout (floats):
//   v      : [BB][DD]              off 0
//   partC  : [BB][NCHUNK][DD]      off 65536          (4 MB)
//   partML : [BB][NCHUNK][2]       off 65536+1048576

// ---------------- kernel 1: v = x_last @ W^T -------------------------------
// 256 blocks x 4 waves; wave = 4 d-rows (W stationary, 64 VGPR) x 16 batches.
__global__ __launch_bounds__(256, 4) void k_v(const float* __restrict__ x,
                                              const float* __restrict__ W,
                                              float* __restrict__ v) {
    const int wave = threadIdx.x >> 6;
    const int lane = threadIdx.x & 63;
    const int wg   = blockIdx.x * 4 + wave;   // 0..1023
    const int d0   = (wg >> 2) * 4;           // 256 d-quads
    const int bg   = wg & 3;                  // 4 batch-groups of 16

    float4 w4[4][4];
#pragma unroll
    for (int k = 0; k < 4; ++k)
#pragma unroll
        for (int j = 0; j < 4; ++j)
            w4[k][j] = *(const float4*)(W + (size_t)(d0 + k) * DD + j * 256 + lane * 4);

    float res = 0.f;                          // lane l -> (b = bg*16+(l>>2), d = d0+(l&3))
#pragma unroll 4
    for (int i = 0; i < 16; ++i) {
        const int b = bg * 16 + i;
        const float* xl = x + ((size_t)b * TT + (TT - 1)) * DD;
        float4 x4[4];
#pragma unroll
        for (int j = 0; j < 4; ++j)
            x4[j] = *(const float4*)(xl + j * 256 + lane * 4);
#pragma unroll
        for (int k = 0; k < 4; ++k) {
            float p = 0.f;
#pragma unroll
            for (int j = 0; j < 4; ++j)
                p += w4[k][j].x * x4[j].x + w4[k][j].y * x4[j].y +
                     w4[k][j].z * x4[j].z + w4[k][j].w * x4[j].w;
#pragma unroll
            for (int m = 1; m < 64; m <<= 1) p += __shfl_xor(p, m, 64);
            if (lane == i * 4 + k) res = p;
        }
    }
    v[(size_t)(bg * 16 + (lane >> 2)) * DD + d0 + (lane & 3)] = res;
}

// ---------------- kernel 2: fused online-softmax chunk kernel --------------
// grid = BB*NCHUNK = 1024 blocks, 256 thr, ~70 VGPR, tiny LDS.
// Per sub-chunk of 16 rows: stream rows from HBM (scores), then re-read the
// hot 64KB from L2 accumulating into a per-thread float4 with online rescale.
__global__ __launch_bounds__(256, 4) void k_chunk(const float* __restrict__ x,
                                                  const float* __restrict__ v,
                                                  float* __restrict__ partC,
                                                  float* __restrict__ partML) {
    __shared__ float sloc[SUB];

    const int b    = blockIdx.x >> 4;           // / NCHUNK
    const int c    = blockIdx.x & (NCHUNK - 1);
    const int wave = threadIdx.x >> 6;
    const int lane = threadIdx.x & 63;
    const int R    = min(CHUNK, TH - c * CHUNK);   // 32, last chunk 31

    float4 v4[4];
#pragma unroll
    for (int j = 0; j < 4; ++j)
        v4[j] = *(const float4*)(v + (size_t)b * DD + j * 256 + lane * 4);

    const float* xb = x + ((size_t)b * TT + (size_t)c * CHUNK) * DD;
    const int d0 = threadIdx.x * 4;

    float m = -INFINITY;
    float l = 0.f;
    float4 acc = make_float4(0.f, 0.f, 0.f, 0.f);

#pragma unroll
    for (int s = 0; s < CHUNK / SUB; ++s) {
        const int Rs = min(SUB, R - s * SUB);   // 16, or 15 for last sub of chunk 15

        // phase A: scores for this sub-chunk (wave owns 4 rows)
        float pp[4] = {0.f, 0.f, 0.f, 0.f};
#pragma unroll
        for (int rl = 0; rl < 4; ++rl) {
            const int r = wave * 4 + rl;
            if (r < Rs) {
                const float* xr = xb + (size_t)(s * SUB + r) * DD;
#pragma unroll
                for (int j = 0; j < 4; ++j) {
                    const float4 xv = *(const float4*)(xr + j * 256 + lane * 4);
                    pp[rl] += v4[j].x * xv.x + v4[j].y * xv.y +
                              v4[j].z * xv.z + v4[j].w * xv.w;
                }
            }
        }
#pragma unroll
        for (int rl = 0; rl < 4; ++rl)
#pragma unroll
            for (int mm = 1; mm < 64; mm <<= 1) pp[rl] += __shfl_xor(pp[rl], mm, 64);
        if (lane == 0) {
#pragma unroll
            for (int rl = 0; rl < 4; ++rl) {
                const int r = wave * 4 + rl;
                if (r < Rs) sloc[r] = pp[rl];
            }
        }
        __syncthreads();

        // phase B: online update, redundant per thread (16 LDS broadcasts + exps)
        float mnew = m;
        for (int r = 0; r < Rs; ++r) mnew = fmaxf(mnew, sloc[r]);
        const float scale = __expf(m - mnew);   // first iter: exp(-inf)=0
        acc.x *= scale; acc.y *= scale; acc.z *= scale; acc.w *= scale;
        l *= scale;

        // phase C: weighted accumulate, rows re-read from hot L2
        for (int r = 0; r < Rs; ++r) {
            const float e = __expf(sloc[r] - mnew);
            l += e;
            const float4 xv = *(const float4*)(xb + (size_t)(s * SUB + r) * DD + d0);
            acc.x += e * xv.x; acc.y += e * xv.y;
            acc.z += e * xv.z; acc.w += e * xv.w;
        }
        m = mnew;
        __syncthreads();
    }

    *(float4*)(partC + ((size_t)b * NCHUNK + c) * DD + d0) = acc;
    if (threadIdx.x == 0) {
        partML[((size_t)b * NCHUNK + c) * 2 + 0] = m;
        partML[((size_t)b * NCHUNK + c) * 2 + 1] = l;
    }
}

// ---------------- kernel 3: combine partials, divide, append x_last --------
__global__ __launch_bounds__(256) void k_final(const float* __restrict__ x,
                                               const float* __restrict__ partC,
                                               const float* __restrict__ partML,
                                               float* __restrict__ out) {
    const int b = blockIdx.x >> 2;
    const int q = blockIdx.x & 3;
    __shared__ float wgt[NCHUNK];
    __shared__ float lsh;

    if (threadIdx.x < NCHUNK) {
        float M = -INFINITY;
        for (int cc = 0; cc < NCHUNK; ++cc)
            M = fmaxf(M, partML[((size_t)b * NCHUNK + cc) * 2]);
        wgt[threadIdx.x] = __expf(partML[((size_t)b * NCHUNK + threadIdx.x) * 2] - M);
    }
    __syncthreads();
    if (threadIdx.x == 0) {
        float L = 0.f;
        for (int cc = 0; cc < NCHUNK; ++cc)
            L += partML[((size_t)b * NCHUNK + cc) * 2 + 1] * wgt[cc];
        lsh = 1.f / L;
    }
    __syncthreads();
    const float invL = lsh;

    const int d = q * 256 + threadIdx.x;
    float acc = 0.f;
#pragma unroll
    for (int cc = 0; cc < NCHUNK; ++cc)
        acc += wgt[cc] * partC[((size_t)b * NCHUNK + cc) * DD + d];
    out[(size_t)b * 2048 + d] = acc * invL;
    out[(size_t)b * 2048 + 1024 + d] = x[((size_t)b * TT + (TT - 1)) * DD + d];
}

extern "C" void kernel_launch(void* const* d_in, const int* in_sizes, int n_in,
                              void* d_out, int out_size, void* d_ws, size_t ws_size,
                              hipStream_t stream) {
    const float* x = (const float*)d_in[0];   // (64,512,1024) fp32
    const float* W = (const float*)d_in[1];   // (1024,1024) fp32
    float* out = (float*)d_out;               // (64,2048) fp32

    float* ws     = (float*)d_ws;
    float* v      = ws;                                           // 65536
    float* partC  = ws + 65536;                                   // 1048576
    float* partML = ws + 65536 + (size_t)BB * NCHUNK * DD;        // 2048

    k_v<<<256, 256, 0, stream>>>(x, W, v);
    k_chunk<<<BB * NCHUNK, 256, 0, stream>>>(x, v, partC, partML);
    k_final<<<BB * 4, 256, 0, stream>>>(x, partC, partML, out);
}

// Round 4
// 49.272 us; speedup vs baseline: 1.3651x; 1.3651x over previous
//
#include <hip/hip_runtime.h>
#include <math.h>

// Problem: B=64, T=512, D=1024.
//   v[b,d]     = sum_e W[d,e] * x[b,T-1,e]
//   scores[b,t]= sum_d x[b,t,d] * v[b,d]          (t in 0..510)
//   alpha      = softmax_t(scores)
//   c[b,d]     = sum_t alpha[b,t] * x[b,t,d]
//   out[b]     = concat(c[b,:], x[b,T-1,:])       (64 x 2048 fp32)

#define BB 64
#define TT 512
#define DD 1024
#define TH 511           // valid history rows: 0..510
#define GROUPS 16        // blocks per batch
#define RPW 8            // rows per wave (4 waves * 8 = 32 rows per block)

// workspace (floats):
//   v      : [BB][DD]          off 0        (65536)
//   partC  : [BB][GROUPS][DD]  off 65536    (1048576)
//   partML : [BB][GROUPS][2]   off 1114112  (2048)

// ---------------- kernel 1: v = x_last @ W^T -------------------------------
// 256 blocks x 4 waves; wave = 4 d-rows (W stationary, 64 VGPR) x 16 batches.
__global__ __launch_bounds__(256, 4) void k_v(const float* __restrict__ x,
                                              const float* __restrict__ W,
                                              float* __restrict__ v) {
    const int wave = threadIdx.x >> 6;
    const int lane = threadIdx.x & 63;
    const int wg   = blockIdx.x * 4 + wave;   // 0..1023
    const int d0   = (wg >> 2) * 4;           // 256 d-quads
    const int bg   = wg & 3;                  // 4 batch-groups of 16

    float4 w4[4][4];
#pragma unroll
    for (int k = 0; k < 4; ++k)
#pragma unroll
        for (int j = 0; j < 4; ++j)
            w4[k][j] = *(const float4*)(W + (size_t)(d0 + k) * DD + j * 256 + lane * 4);

    float res = 0.f;                          // lane l -> (b = bg*16+(l>>2), d = d0+(l&3))
#pragma unroll 4
    for (int i = 0; i < 16; ++i) {
        const int b = bg * 16 + i;
        const float* xl = x + ((size_t)b * TT + (TT - 1)) * DD;
        float4 x4[4];
#pragma unroll
        for (int j = 0; j < 4; ++j)
            x4[j] = *(const float4*)(xl + j * 256 + lane * 4);
#pragma unroll
        for (int k = 0; k < 4; ++k) {
            float p = 0.f;
#pragma unroll
            for (int j = 0; j < 4; ++j)
                p += w4[k][j].x * x4[j].x + w4[k][j].y * x4[j].y +
                     w4[k][j].z * x4[j].z + w4[k][j].w * x4[j].w;
#pragma unroll
            for (int m = 1; m < 64; m <<= 1) p += __shfl_xor(p, m, 64);
            if (lane == i * 4 + k) res = p;
        }
    }
    v[(size_t)(bg * 16 + (lane >> 2)) * DD + d0 + (lane & 3)] = res;
}

// ---------------- kernel 2: wave-autonomous flash chunk --------------------
// 1024 blocks (64 b x 16 groups), 256 thr. Each wave: 8 rows, online softmax
// fully in registers, one-row-ahead prefetch, NO barriers in hot loop.
__global__ __launch_bounds__(256, 4) void k_chunk(const float* __restrict__ x,
                                                  const float* __restrict__ v,
                                                  float* __restrict__ partC,
                                                  float* __restrict__ partML) {
    __shared__ float cw[4][DD];               // 16 KB combine buffer
    __shared__ float cml[4][2];

    const int b    = blockIdx.x >> 4;
    const int g    = blockIdx.x & (GROUPS - 1);
    const int wave = threadIdx.x >> 6;
    const int lane = threadIdx.x & 63;
    const int r0   = g * 32 + wave * RPW;     // first row; <= 504, always valid
    const int col  = lane * 4;

    const float* xb = x + (size_t)b * TT * DD;

    float4 v4[4];
#pragma unroll
    for (int j = 0; j < 4; ++j)
        v4[j] = *(const float4*)(v + (size_t)b * DD + j * 256 + col);

    float4 xa[4], xn[4];
#pragma unroll
    for (int j = 0; j < 4; ++j)
        xa[j] = *(const float4*)(xb + (size_t)r0 * DD + j * 256 + col);

    float m = -INFINITY, l = 0.f;
    float4 acc[4] = {make_float4(0,0,0,0), make_float4(0,0,0,0),
                     make_float4(0,0,0,0), make_float4(0,0,0,0)};

#pragma unroll
    for (int i = 0; i < RPW; ++i) {
        // prefetch next row (clamped address; validity handled via score)
        if (i < RPW - 1) {
            const int rn = min(r0 + i + 1, TH - 1);
#pragma unroll
            for (int j = 0; j < 4; ++j)
                xn[j] = *(const float4*)(xb + (size_t)rn * DD + j * 256 + col);
        }

        // score of current row
        float s = 0.f;
#pragma unroll
        for (int j = 0; j < 4; ++j)
            s += v4[j].x * xa[j].x + v4[j].y * xa[j].y +
                 v4[j].z * xa[j].z + v4[j].w * xa[j].w;
#pragma unroll
        for (int mm = 1; mm < 64; mm <<= 1) s += __shfl_xor(s, mm, 64);
        if (r0 + i >= TH) s = -INFINITY;      // invalid tail row -> e = 0

        const float mnew = fmaxf(m, s);
        if (mnew > m) {                        // wave-uniform branch (butterfly
            const float scale = __expf(m - mnew);  // gives identical s per lane)
#pragma unroll
            for (int j = 0; j < 4; ++j) {
                acc[j].x *= scale; acc[j].y *= scale;
                acc[j].z *= scale; acc[j].w *= scale;
            }
            l *= scale;
            m = mnew;
        }
        const float e = __expf(s - m);
        l += e;
#pragma unroll
        for (int j = 0; j < 4; ++j) {
            acc[j].x += e * xa[j].x; acc[j].y += e * xa[j].y;
            acc[j].z += e * xa[j].z; acc[j].w += e * xa[j].w;
        }
        if (i < RPW - 1) {
#pragma unroll
            for (int j = 0; j < 4; ++j) xa[j] = xn[j];
        }
    }

    // one cross-wave combine per block
#pragma unroll
    for (int j = 0; j < 4; ++j)
        *(float4*)(&cw[wave][j * 256 + col]) = acc[j];
    if (lane == 0) { cml[wave][0] = m; cml[wave][1] = l; }
    __syncthreads();

    float M = fmaxf(fmaxf(cml[0][0], cml[1][0]), fmaxf(cml[2][0], cml[3][0]));
    float w0 = __expf(cml[0][0] - M), w1 = __expf(cml[1][0] - M);
    float w2 = __expf(cml[2][0] - M), w3 = __expf(cml[3][0] - M);
    const float L = w0 * cml[0][1] + w1 * cml[1][1] + w2 * cml[2][1] + w3 * cml[3][1];

    const int d0 = threadIdx.x * 4;
    const float4 s0 = *(const float4*)(&cw[0][d0]);
    const float4 s1 = *(const float4*)(&cw[1][d0]);
    const float4 s2 = *(const float4*)(&cw[2][d0]);
    const float4 s3 = *(const float4*)(&cw[3][d0]);
    float4 o;
    o.x = w0 * s0.x + w1 * s1.x + w2 * s2.x + w3 * s3.x;
    o.y = w0 * s0.y + w1 * s1.y + w2 * s2.y + w3 * s3.y;
    o.z = w0 * s0.z + w1 * s1.z + w2 * s2.z + w3 * s3.z;
    o.w = w0 * s0.w + w1 * s1.w + w2 * s2.w + w3 * s3.w;
    *(float4*)(partC + ((size_t)b * GROUPS + g) * DD + d0) = o;
    if (threadIdx.x == 0) {
        partML[((size_t)b * GROUPS + g) * 2 + 0] = M;
        partML[((size_t)b * GROUPS + g) * 2 + 1] = L;
    }
}

// ---------------- kernel 3: combine partials, divide, append x_last --------
__global__ __launch_bounds__(256) void k_final(const float* __restrict__ x,
                                               const float* __restrict__ partC,
                                               const float* __restrict__ partML,
                                               float* __restrict__ out) {
    const int b = blockIdx.x >> 2;
    const int q = blockIdx.x & 3;
    __shared__ float wgt[GROUPS];
    __shared__ float lsh;

    if (threadIdx.x < GROUPS) {
        float M = -INFINITY;
        for (int cc = 0; cc < GROUPS; ++cc)
            M = fmaxf(M, partML[((size_t)b * GROUPS + cc) * 2]);
        wgt[threadIdx.x] = __expf(partML[((size_t)b * GROUPS + threadIdx.x) * 2] - M);
    }
    __syncthreads();
    if (threadIdx.x == 0) {
        float L = 0.f;
        for (int cc = 0; cc < GROUPS; ++cc)
            L += partML[((size_t)b * GROUPS + cc) * 2 + 1] * wgt[cc];
        lsh = 1.f / L;
    }
    __syncthreads();
    const float invL = lsh;

    const int d = q * 256 + threadIdx.x;
    float acc = 0.f;
#pragma unroll
    for (int cc = 0; cc < GROUPS; ++cc)
        acc += wgt[cc] * partC[((size_t)b * GROUPS + cc) * DD + d];
    out[(size_t)b * 2048 + d] = acc * invL;
    out[(size_t)b * 2048 + 1024 + d] = x[((size_t)b * TT + (TT - 1)) * DD + d];
}

extern "C" void kernel_launch(void* const* d_in, const int* in_sizes, int n_in,
                              void* d_out, int out_size, void* d_ws, size_t ws_size,
                              hipStream_t stream) {
    const float* x = (const float*)d_in[0];   // (64,512,1024) fp32
    const float* W = (const float*)d_in[1];   // (1024,1024) fp32
    float* out = (float*)d_out;               // (64,2048) fp32

    float* ws     = (float*)d_ws;
    float* v      = ws;                                           // 65536
    float* partC  = ws + 65536;                                   // 1048576
    float* partML = ws + 65536 + (size_t)BB * GROUPS * DD;        // 2048

    k_v<<<256, 256, 0, stream>>>(x, W, v);
    k_chunk<<<BB * GROUPS, 256, 0, stream>>>(x, v, partC, partML);
    k_final<<<BB * 4, 256, 0, stream>>>(x, partC, partML, out);
}